// Round 4
// baseline (377.726 us; speedup 1.0000x reference)
//
#include <hip/hip_runtime.h>
#include <math.h>

#define C_IN  512
#define WDIM  128

// ---------------- wave-wide sum: DPP within 16, swizzle/bpermute across ----------------
// (proven in the 376.3us baseline — unchanged)
__device__ __forceinline__ float wave_sum(float v) {
    int t;
    // row_ror:8  — lane i += lane (i+8)%16 within its row of 16
    t = __builtin_amdgcn_update_dpp(0, __float_as_int(v), 0x128, 0xF, 0xF, true);
    v += __int_as_float(t);
    // row_ror:4
    t = __builtin_amdgcn_update_dpp(0, __float_as_int(v), 0x124, 0xF, 0xF, true);
    v += __int_as_float(t);
    // quad_perm [2,3,0,1] = xor2
    t = __builtin_amdgcn_update_dpp(0, __float_as_int(v), 0x4E, 0xF, 0xF, true);
    v += __int_as_float(t);
    // quad_perm [1,0,3,2] = xor1
    t = __builtin_amdgcn_update_dpp(0, __float_as_int(v), 0xB1, 0xF, 0xF, true);
    v += __int_as_float(t);
    // xor16 via ds_swizzle (BitMode: offset = xor<<10 | and 0x1F)
    v += __int_as_float(__builtin_amdgcn_ds_swizzle(__float_as_int(v), 0x401F));
    // cross-32 half (ds_bpermute across full wave64)
    v += __shfl_xor(v, 32, 64);
    return v;
}

__device__ __forceinline__ float fast_tanh(float x) {
    // tanh(x) = 1 - 2/(e^{2x}+1); exact at +/-inf, ~1e-6 rel error (threshold 2e-2)
    float e = __expf(2.0f * x);
    return 1.0f - 2.0f / (e + 1.0f);
}

// ---------------- Fused persistent kernel ----------------
// 256 blocks x 1024 threads = exactly 1 block/CU (16 waves). Each block owns
// 512 pixels (32 px/wave); 32 blocks per image. Phase-1 aw redundancy:
// 256 x 256 KB = 64 MB of L2 reads (~2 us burst). Phase 2: wave-per-pixel
// split-K with an explicit depth-2-pair load pipeline (4 px / 8 x-loads in
// flight per wave -> load queue stays full across the reduce chain).
__global__ __launch_bounds__(1024) void torgb_fused(
    const float* __restrict__ x, const float* __restrict__ w,
    const float* __restrict__ aw, const float* __restrict__ ab,
    const float* __restrict__ k2d, const float* __restrict__ bias,
    float* __restrict__ out)
{
    __shared__ __align__(16) float keS[4][C_IN];   // [c_out][c_in], 8 KB
    __shared__ float pS[2 * C_IN];                 // partial dots, 4 KB

    const int tid = threadIdx.x;
    const int b   = blockIdx.x >> 5;               // 32 blocks per image (512 px each)

    // ---- Phase 1: effective kernel for this image -> LDS ----
    {
        const int h = tid >> 9;                    // row-half: 0 or 1
        const int c = tid & 511;                   // channel
        const float* __restrict__ wr = w + b * WDIM + h * 64;   // wave-uniform
        const float* __restrict__ ap = aw + (size_t)(h * 64) * C_IN + c;
        float s = 0.f;
        #pragma unroll 8
        for (int j = 0; j < 64; ++j)
            s = fmaf(wr[j], ap[j * C_IN], s);      // coalesced across lanes
        pS[h * C_IN + c] = s;
    }
    __syncthreads();
    if (tid < C_IN) {
        const float s = (pS[tid] + pS[C_IN + tid] + ab[tid]) * 0.04419417382415922f; // 1/sqrt(512)
        const float4 kk = ((const float4*)k2d)[tid];
        keS[0][tid] = s * kk.x; keS[1][tid] = s * kk.y;
        keS[2][tid] = s * kk.z; keS[3][tid] = s * kk.w;
    }
    __syncthreads();

    const int lane = tid & 63;
    // Per-lane fragments: ka[o] = ke[o][4l..4l+3], kb[o] = ke[o][256+4l..256+4l+3]
    float4 ka[4], kb[4];
    #pragma unroll
    for (int o = 0; o < 4; ++o) {
        ka[o] = ((const float4*)&keS[o][0])[lane];
        kb[o] = ((const float4*)&keS[o][256])[lane];
    }
    const float4 bb = *(const float4*)bias;
    float4* __restrict__ out4 = (float4*)out;

    const int wave_g   = (blockIdx.x << 4) | (tid >> 6);   // 16 waves/block
    const int pix_base = wave_g << 5;                      // 32 px per wave
    const float* __restrict__ xq = x + (size_t)pix_base * C_IN;

#define XROW(i) ((const float4*)(xq + (size_t)(i) * C_IN))
#define COMPUTE_STORE(XA, XB, PIX)                                                                  \
    {                                                                                               \
        float a0, a1, a2, a3;                                                                       \
        a0 = fmaf((XA).x, ka[0].x, fmaf((XA).y, ka[0].y, fmaf((XA).z, ka[0].z, (XA).w * ka[0].w))); \
        a1 = fmaf((XA).x, ka[1].x, fmaf((XA).y, ka[1].y, fmaf((XA).z, ka[1].z, (XA).w * ka[1].w))); \
        a2 = fmaf((XA).x, ka[2].x, fmaf((XA).y, ka[2].y, fmaf((XA).z, ka[2].z, (XA).w * ka[2].w))); \
        a3 = fmaf((XA).x, ka[3].x, fmaf((XA).y, ka[3].y, fmaf((XA).z, ka[3].z, (XA).w * ka[3].w))); \
        a0 = fmaf((XB).x, kb[0].x, fmaf((XB).y, kb[0].y, fmaf((XB).z, kb[0].z, fmaf((XB).w, kb[0].w, a0)))); \
        a1 = fmaf((XB).x, kb[1].x, fmaf((XB).y, kb[1].y, fmaf((XB).z, kb[1].z, fmaf((XB).w, kb[1].w, a1)))); \
        a2 = fmaf((XB).x, kb[2].x, fmaf((XB).y, kb[2].y, fmaf((XB).z, kb[2].z, fmaf((XB).w, kb[2].w, a2)))); \
        a3 = fmaf((XB).x, kb[3].x, fmaf((XB).y, kb[3].y, fmaf((XB).z, kb[3].z, fmaf((XB).w, kb[3].w, a3)))); \
        a0 = wave_sum(a0);                                                                          \
        a1 = wave_sum(a1);                                                                          \
        a2 = wave_sum(a2);                                                                          \
        a3 = wave_sum(a3);                                                                          \
        if (lane == 0) {                                                                            \
            float4 o;                                                                               \
            o.x = fast_tanh(a0 + bb.x);                                                             \
            o.y = fast_tanh(a1 + bb.y);                                                             \
            o.z = fast_tanh(a2 + bb.z);                                                             \
            o.w = fast_tanh(a3 + bb.w);                                                             \
            out4[PIX] = o;                                                                          \
        }                                                                                           \
    }

    // prologue: pixels 0,1 in flight
    float4 A0 = XROW(0)[lane], B0 = XROW(0)[64 + lane];
    float4 A1 = XROW(1)[lane], B1 = XROW(1)[64 + lane];

    // steady state: i = 0..28 step 2, unconditional prefetch of i+2, i+3
    #pragma unroll 3
    for (int i = 0; i <= 28; i += 2) {
        float4 A2 = XROW(i + 2)[lane], B2 = XROW(i + 2)[64 + lane];
        float4 A3 = XROW(i + 3)[lane], B3 = XROW(i + 3)[64 + lane];
        COMPUTE_STORE(A0, B0, pix_base + i);
        COMPUTE_STORE(A1, B1, pix_base + i + 1);
        A0 = A2; B0 = B2; A1 = A3; B1 = B3;
    }
    // epilogue: pixels 30,31 (prefetched by the i=28 iteration)
    COMPUTE_STORE(A0, B0, pix_base + 30);
    COMPUTE_STORE(A1, B1, pix_base + 31);

#undef COMPUTE_STORE
#undef XROW
}

extern "C" void kernel_launch(void* const* d_in, const int* in_sizes, int n_in,
                              void* d_out, int out_size, void* d_ws, size_t ws_size,
                              hipStream_t stream) {
    const float* x    = (const float*)d_in[0];   // [8,128,128,512]
    const float* w    = (const float*)d_in[1];   // [8,128]
    const float* aw   = (const float*)d_in[2];   // [128,512]
    const float* ab   = (const float*)d_in[3];   // [512]
    const float* kk   = (const float*)d_in[4];   // [1,1,512,4]
    const float* bias = (const float*)d_in[5];   // [4]
    float* out = (float*)d_out;                  // [8,128,128,4] fp32
    (void)d_ws; (void)ws_size;

    // 131072 pixels / (32 px/wave * 16 waves/block) = 256 blocks = 1 per CU
    hipLaunchKernelGGL(torgb_fused, dim3(256), dim3(1024), 0, stream,
                       x, w, aw, ab, kk, bias, out);
}